// Round 5
// baseline (2070.806 us; speedup 1.0000x reference)
//
#include <hip/hip_runtime.h>

#define CODES_ELEMS 8388608   // 16*1024*512
#define N_ROWS      131072    // 16*1024*8
#define IDX_OFF     CODES_ELEMS
#define LOSS_OFF    (CODES_ELEMS + N_ROWS)

// d_ws: [0,4) fp32 loss accumulator; [64, 64+8192) cc[2048] = ||c_k||^2

// cc[k] = sum_d c[k][d]^2, fp32, butterfly tree IDENTICAL to round 4 (bit-stable).
__global__ __launch_bounds__(256) void vq_prep(const float* __restrict__ cb,
                                               float* __restrict__ cc,
                                               float* __restrict__ loss_acc) {
  int t = threadIdx.x;
  if (blockIdx.x == 0 && t == 0) loss_acc[0] = 0.f;
  int e = blockIdx.x * 256 + t;          // 512*256 = 2048 codes * 64 dims
  float v = cb[e];
  float s = v * v;
  #pragma unroll
  for (int m = 1; m < 64; m <<= 1) s += __shfl_xor(s, m, 64);
  if ((t & 63) == 0) cc[e >> 6] = s;
}

// Block = 64 z-rows x 2048 codes (16 chunks of 128). Thread tile 4 rows x 8 codes.
// LDS tiles transposed [d][.] with XOR-quad swizzle q' = q ^ ((d>>3)&7):
// staging writes and float4 reads are <=2-way bank aliased (free, m136).
__global__ __launch_bounds__(256, 3) void VQQuantizer_30064771072206_kernel(
    const float* __restrict__ zf, const float* __restrict__ cb,
    const float* __restrict__ cc, float* __restrict__ loss_acc,
    float* __restrict__ out)
{
  __shared__ __align__(16) float zt[4096];   // 64 d x 64 rows (swizzled), 16KB
  __shared__ __align__(16) float ct[8192];   // 64 d x 128 codes (swizzled), 32KB
  __shared__ float cc_l[128];
  __shared__ float zz_l[64];
  __shared__ int   idxbuf[64];
  __shared__ float wsum[4];
  const int t  = threadIdx.x;
  const int tx = t & 15;                     // code-group selector
  const int ty = t >> 4;                     // row-quad selector (0..15)
  const int R0 = blockIdx.x * 64;
  const float4* zf4 = (const float4*)zf;
  const float4* cb4 = (const float4*)cb;

  // ---- stage z tile (64x64) transposed+swizzled; coalesced float4 reads
  #pragma unroll
  for (int i = 0; i < 4; ++i) {
    int f = i * 256 + t;
    int r = f >> 4, dq = f & 15;
    float4 v = zf4[(size_t)(R0 + r) * 16 + dq];
    float vv[4] = {v.x, v.y, v.z, v.w};
    #pragma unroll
    for (int j = 0; j < 4; ++j) {
      int d = dq * 4 + j;
      int s = (d >> 3) & 7;
      zt[d * 64 + ((((r >> 2) ^ s) << 2) | (r & 3))] = vv[j];
    }
  }
  __syncthreads();
  if (t < 64) {                              // zz: sequential d order == round 4
    float s = 0.f;
    for (int d = 0; d < 64; ++d) {
      float v = zt[d * 64 + ((((t >> 2) ^ ((d >> 3) & 7)) << 2) | (t & 3))];
      s += v * v;
    }
    zz_l[t] = s;
  }
  __syncthreads();
  float zz_r[4];
  #pragma unroll
  for (int i = 0; i < 4; ++i) zz_r[i] = zz_l[ty * 4 + i];

  float bestv[4] = {3.402823466e38f, 3.402823466e38f, 3.402823466e38f, 3.402823466e38f};
  int   besti[4] = {0, 0, 0, 0};

  for (int chunk = 0; chunk < 16; ++chunk) {
    // prefetch chunk (coalesced, issued before the barrier)
    float4 cv[8];
    #pragma unroll
    for (int i = 0; i < 8; ++i) {
      int f = i * 256 + t;
      cv[i] = cb4[(size_t)(chunk * 128 + (f >> 4)) * 16 + (f & 15)];
    }
    float ccreg = (t < 128) ? cc[chunk * 128 + t] : 0.f;
    if (chunk) __syncthreads();              // prior chunk fully consumed
    #pragma unroll
    for (int i = 0; i < 8; ++i) {
      int f = i * 256 + t;
      int code = f >> 4, dq = f & 15;
      float vv[4] = {cv[i].x, cv[i].y, cv[i].z, cv[i].w};
      #pragma unroll
      for (int j = 0; j < 4; ++j) {
        int d = dq * 4 + j;
        int s = (d >> 3) & 7;
        ct[d * 128 + ((((code >> 2) ^ s) << 2) | (code & 3))] = vv[j];
      }
    }
    if (t < 128) cc_l[t] = ccreg;
    __syncthreads();

    float acc[4][8];
    #pragma unroll
    for (int i = 0; i < 4; ++i)
      #pragma unroll
      for (int j = 0; j < 8; ++j) acc[i][j] = 0.f;

    // thread's codes: quad tx (codes tx*4..+3) and quad 16+tx (codes 64+tx*4..+3)
    #pragma unroll
    for (int d8 = 0; d8 < 8; ++d8) {
      const int s = d8 & 7;
      const int zoff = ((ty ^ s) << 2);
      const int aoff = ((tx ^ s) << 2);
      const int boff = (((16 + tx) ^ s) << 2);
      #pragma unroll
      for (int dd = 0; dd < 8; ++dd) {
        const int d = d8 * 8 + dd;           // ascending d: same acc order as round 4
        float4 zv = *(const float4*)&zt[d * 64 + zoff];
        float4 ca = *(const float4*)&ct[d * 128 + aoff];
        float4 cbv = *(const float4*)&ct[d * 128 + boff];
        float zr[4] = {zv.x, zv.y, zv.z, zv.w};
        float cr[8] = {ca.x, ca.y, ca.z, ca.w, cbv.x, cbv.y, cbv.z, cbv.w};
        #pragma unroll
        for (int i = 0; i < 4; ++i)
          #pragma unroll
          for (int j = 0; j < 8; ++j) acc[i][j] += zr[i] * cr[j];
      }
    }
    // dist = fl(zz - 2*acc) + cc, ascending code order per thread (np tie semantics)
    #pragma unroll
    for (int j = 0; j < 8; ++j) {
      int code = chunk * 128 + ((j < 4) ? (tx * 4 + j) : (64 + tx * 4 + (j - 4)));
      float ccv = cc_l[(j < 4) ? (tx * 4 + j) : (64 + tx * 4 + (j - 4))];
      #pragma unroll
      for (int i = 0; i < 4; ++i) {
        float t1 = zz_r[i] - 2.0f * acc[i][j];
        float dist = t1 + ccv;
        if (dist < bestv[i]) { bestv[i] = dist; besti[i] = code; }
      }
    }
  }

  // merge across the 16 consecutive lanes sharing a row quad (lowest-index ties)
  #pragma unroll
  for (int i = 0; i < 4; ++i) {
    float v = bestv[i]; int idx = besti[i];
    #pragma unroll
    for (int m = 1; m < 16; m <<= 1) {
      float ov = __shfl_xor(v, m, 64);
      int   oi = __shfl_xor(idx, m, 64);
      if (ov < v || (ov == v && oi < idx)) { v = ov; idx = oi; }
    }
    if (tx == 0) idxbuf[ty * 4 + i] = idx;
  }
  __syncthreads();

  if (t < 64) out[IDX_OFF + R0 + t] = (float)idxbuf[t];

  // codes = zg + (zq - zg) (same fp ops as np/round 4); loss fp32; all float4
  float lsum = 0.f;
  float4* out4 = (float4*)out;
  #pragma unroll
  for (int i = 0; i < 4; ++i) {
    int f = i * 256 + t;
    int row = f >> 4, dq = f & 15;
    int k = idxbuf[row];                     // uniform per 16 lanes -> broadcast
    float4 q  = cb4[(size_t)k * 16 + dq];
    float4 zv = zf4[(size_t)(R0 + row) * 16 + dq];
    float dx = q.x - zv.x, dy = q.y - zv.y, dz = q.z - zv.z, dw = q.w - zv.w;
    float4 st; st.x = zv.x + dx; st.y = zv.y + dy; st.z = zv.z + dz; st.w = zv.w + dw;
    out4[(size_t)(R0 + row) * 16 + dq] = st;
    lsum += dx * dx; lsum += dy * dy; lsum += dz * dz; lsum += dw * dw;
  }
  #pragma unroll
  for (int m = 1; m < 64; m <<= 1) lsum += __shfl_xor(lsum, m, 64);
  if ((t & 63) == 0) wsum[t >> 6] = lsum;
  __syncthreads();
  if (t == 0) atomicAdd(loss_acc, wsum[0] + wsum[1] + wsum[2] + wsum[3]);
}

__global__ void vq_finalize(const float* __restrict__ loss_acc,
                            float* __restrict__ out) {
  out[LOSS_OFF] = loss_acc[0] * (1.f / 8388608.f);
}

extern "C" void kernel_launch(void* const* d_in, const int* in_sizes, int n_in,
                              void* d_out, int out_size, void* d_ws, size_t ws_size,
                              hipStream_t stream) {
  const float* z  = (const float*)d_in[0];
  const float* cb = (const float*)d_in[1];
  float* out = (float*)d_out;
  float* loss_acc = (float*)d_ws;
  float* cc       = (float*)((char*)d_ws + 64);

  vq_prep<<<512, 256, 0, stream>>>(cb, cc, loss_acc);
  VQQuantizer_30064771072206_kernel<<<2048, 256, 0, stream>>>(z, cb, cc, loss_acc, out);
  vq_finalize<<<1, 1, 0, stream>>>(loss_acc, out);
}

// Round 6
// 533.221 us; speedup vs baseline: 3.8836x; 3.8836x over previous
//
#include <hip/hip_runtime.h>

#define CODES_ELEMS 8388608   // 16*1024*512
#define N_ROWS      131072    // 16*1024*8
#define IDX_OFF     CODES_ELEMS
#define LOSS_OFF    (CODES_ELEMS + N_ROWS)

// d_ws: [0,4) fp32 loss acc; [64,8256) cc[2048]; [8448, 8448+524288) cbt
// cbt = chunk-tiled transposed codebook: [chunk(16)][d(64)][code(128)] fp32.
#define WS_CC   64
#define WS_CBT  8448

// One pass over the codebook: emit cc[k] = sum_d c[k][d]^2 (butterfly order
// IDENTICAL to rounds 4/5 - bit-stable) and the chunk-tiled transpose.
__global__ __launch_bounds__(256) void vq_prep(const float* __restrict__ cb,
                                               float* __restrict__ cc,
                                               float* __restrict__ cbt,
                                               float* __restrict__ loss_acc) {
  int t = threadIdx.x;
  if (blockIdx.x == 0 && t == 0) loss_acc[0] = 0.f;
  int e = blockIdx.x * 256 + t;          // 512*256 = 2048 codes * 64 dims
  float v = cb[e];
  int k = e >> 6, d = e & 63;
  cbt[(k >> 7) * 8192 + d * 128 + (k & 127)] = v;   // one-time scatter
  float s = v * v;
  #pragma unroll
  for (int m = 1; m < 64; m <<= 1) s += __shfl_xor(s, m, 64);
  if ((t & 63) == 0) cc[k] = s;
}

// Block = 64 z-rows x 2048 codes (16 chunks of 128). Thread tile 4 rows x 8 codes.
// zt row-major [row][d] (identity-staged); ct transposed [d][code] (identity-
// staged from cbt). All LDS traffic <=2-way bank aliased (free, m136).
__global__ __launch_bounds__(256) void VQQuantizer_30064771072206_kernel(
    const float* __restrict__ zf, const float* __restrict__ cb,
    const float* __restrict__ cbt, const float* __restrict__ cc,
    float* __restrict__ loss_acc, float* __restrict__ out)
{
  __shared__ __align__(16) float zt[4096];   // 64 rows x 64 d, 16KB
  __shared__ __align__(16) float ct[8192];   // 64 d x 128 codes, 32KB
  __shared__ float cc_l[128];
  __shared__ float zz_l[64];
  __shared__ int   idxbuf[64];
  __shared__ float wsum[4];
  const int t  = threadIdx.x;
  const int tx = t & 15;                     // code-octet selector
  const int ty = t >> 4;                     // row-quad selector (0..15)
  const int R0 = blockIdx.x * 64;
  const float4* zf4  = (const float4*)zf;
  const float4* cb4  = (const float4*)cb;
  const float4* cbt4 = (const float4*)cbt;
  float4* zt4 = (float4*)zt;
  float4* ct4 = (float4*)ct;

  // stage z tile: identity copy, coalesced, lane-contiguous (2-way banks, free)
  #pragma unroll
  for (int i = 0; i < 4; ++i)
    zt4[i * 256 + t] = zf4[(size_t)R0 * 16 + i * 256 + t];
  __syncthreads();

  // zz per row: sequential d order, same expression as rounds 4/5 (bit-stable)
  if (t < 64) {
    float s = 0.f;
    for (int d = 0; d < 64; ++d) {
      float v = zt[t * 64 + d];
      s += v * v;
    }
    zz_l[t] = s;
  }
  __syncthreads();
  float zz_r[4];
  #pragma unroll
  for (int i = 0; i < 4; ++i) zz_r[i] = zz_l[ty * 4 + i];

  float bestv[4] = {3.402823466e38f, 3.402823466e38f, 3.402823466e38f, 3.402823466e38f};
  int   besti[4] = {0, 0, 0, 0};

  for (int chunk = 0; chunk < 16; ++chunk) {
    if (chunk) __syncthreads();              // prior chunk fully consumed
    // load->immediate-store staging: no registers live across compute
    #pragma unroll
    for (int i = 0; i < 8; ++i)
      ct4[i * 256 + t] = cbt4[(size_t)chunk * 2048 + i * 256 + t];
    if (t < 128) cc_l[t] = cc[chunk * 128 + t];
    __syncthreads();

    float acc[4][8];
    #pragma unroll
    for (int i = 0; i < 4; ++i)
      #pragma unroll
      for (int j = 0; j < 8; ++j) acc[i][j] = 0.f;

    #pragma unroll 2
    for (int dg = 0; dg < 16; ++dg) {        // 4 d's per iteration, ascending
      float za[4][4];
      #pragma unroll
      for (int i = 0; i < 4; ++i) {          // broadcast reads (free)
        float4 zv = *(const float4*)&zt[(ty * 4 + i) * 64 + dg * 4];
        za[i][0] = zv.x; za[i][1] = zv.y; za[i][2] = zv.z; za[i][3] = zv.w;
      }
      #pragma unroll
      for (int dd = 0; dd < 4; ++dd) {       // d = dg*4+dd ascending (bit-stable)
        const float* crow = &ct[(dg * 4 + dd) * 128];
        float4 ca = *(const float4*)&crow[tx * 4];        // 2-way banks (free)
        float4 cbv = *(const float4*)&crow[64 + tx * 4];
        float cr[8] = {ca.x, ca.y, ca.z, ca.w, cbv.x, cbv.y, cbv.z, cbv.w};
        #pragma unroll
        for (int i = 0; i < 4; ++i)
          #pragma unroll
          for (int j = 0; j < 8; ++j)
            acc[i][j] += za[i][dd] * cr[j];
      }
    }

    // dist = fl(zz - 2*acc) + cc; ascending code order per thread (np ties)
    #pragma unroll
    for (int j = 0; j < 8; ++j) {
      int cloc = (j < 4) ? (tx * 4 + j) : (64 + tx * 4 + (j - 4));
      int code = chunk * 128 + cloc;
      float ccv = cc_l[cloc];
      #pragma unroll
      for (int i = 0; i < 4; ++i) {
        float t1 = zz_r[i] - 2.0f * acc[i][j];
        float dist = t1 + ccv;
        if (dist < bestv[i]) { bestv[i] = dist; besti[i] = code; }
      }
    }
  }

  // merge across the 16 consecutive lanes sharing a row quad (lowest-index ties)
  #pragma unroll
  for (int i = 0; i < 4; ++i) {
    float v = bestv[i]; int idx = besti[i];
    #pragma unroll
    for (int m = 1; m < 16; m <<= 1) {
      float ov = __shfl_xor(v, m, 64);
      int   oi = __shfl_xor(idx, m, 64);
      if (ov < v || (ov == v && oi < idx)) { v = ov; idx = oi; }
    }
    if (tx == 0) idxbuf[ty * 4 + i] = idx;
  }
  __syncthreads();

  if (t < 64) out[IDX_OFF + R0 + t] = (float)idxbuf[t];

  // codes = zg + (zq - zg) (same fp ops as np); loss fp32; all float4
  float lsum = 0.f;
  float4* out4 = (float4*)out;
  #pragma unroll
  for (int i = 0; i < 4; ++i) {
    int f = i * 256 + t;
    int row = f >> 4, dq = f & 15;
    int k = idxbuf[row];                     // uniform per 16 lanes -> broadcast
    float4 q  = cb4[(size_t)k * 16 + dq];
    float4 zv = zf4[(size_t)(R0 + row) * 16 + dq];
    float dx = q.x - zv.x, dy = q.y - zv.y, dz = q.z - zv.z, dw = q.w - zv.w;
    float4 st; st.x = zv.x + dx; st.y = zv.y + dy; st.z = zv.z + dz; st.w = zv.w + dw;
    out4[(size_t)(R0 + row) * 16 + dq] = st;
    lsum += dx * dx; lsum += dy * dy; lsum += dz * dz; lsum += dw * dw;
  }
  #pragma unroll
  for (int m = 1; m < 64; m <<= 1) lsum += __shfl_xor(lsum, m, 64);
  if ((t & 63) == 0) wsum[t >> 6] = lsum;
  __syncthreads();
  if (t == 0) atomicAdd(loss_acc, wsum[0] + wsum[1] + wsum[2] + wsum[3]);
}

__global__ void vq_finalize(const float* __restrict__ loss_acc,
                            float* __restrict__ out) {
  out[LOSS_OFF] = loss_acc[0] * (1.f / 8388608.f);
}

extern "C" void kernel_launch(void* const* d_in, const int* in_sizes, int n_in,
                              void* d_out, int out_size, void* d_ws, size_t ws_size,
                              hipStream_t stream) {
  const float* z  = (const float*)d_in[0];
  const float* cb = (const float*)d_in[1];
  float* out = (float*)d_out;
  float* loss_acc = (float*)d_ws;
  float* cc       = (float*)((char*)d_ws + WS_CC);
  float* cbt      = (float*)((char*)d_ws + WS_CBT);

  vq_prep<<<512, 256, 0, stream>>>(cb, cc, cbt, loss_acc);
  VQQuantizer_30064771072206_kernel<<<2048, 256, 0, stream>>>(z, cb, cbt, cc, loss_acc, out);
  vq_finalize<<<1, 1, 0, stream>>>(loss_acc, out);
}

// Round 7
// 468.911 us; speedup vs baseline: 4.4162x; 1.1371x over previous
//
#include <hip/hip_runtime.h>

typedef float f32x2 __attribute__((ext_vector_type(2)));
typedef float f32x4 __attribute__((ext_vector_type(4)));

#define CODES_ELEMS 8388608   // 16*1024*512
#define N_ROWS      131072    // 16*1024*8
#define IDX_OFF     CODES_ELEMS
#define LOSS_OFF    (CODES_ELEMS + N_ROWS)

// d_ws: [0,4) fp32 loss acc; [64,8256) cc[2048]; [8448, +524288) cbt
// cbt = chunk-tiled transposed codebook: [chunk(16)][d(64)][code(128)] fp32.
#define WS_CC   64
#define WS_CBT  8448

// One pass over the codebook: cc[k] = sum_d c[k][d]^2 (butterfly order,
// bit-identical to rounds 4-6) + chunk-tiled transpose for identity staging.
__global__ __launch_bounds__(256) void vq_prep(const float* __restrict__ cb,
                                               float* __restrict__ cc,
                                               float* __restrict__ cbt,
                                               float* __restrict__ loss_acc) {
  int t = threadIdx.x;
  if (blockIdx.x == 0 && t == 0) loss_acc[0] = 0.f;
  int e = blockIdx.x * 256 + t;          // 512*256 = 2048 codes * 64 dims
  float v = cb[e];
  int k = e >> 6, d = e & 63;
  cbt[(k >> 7) * 8192 + d * 128 + (k & 127)] = v;   // one-time scatter
  float s = v * v;
  #pragma unroll
  for (int m = 1; m < 64; m <<= 1) s += __shfl_xor(s, m, 64);
  if ((t & 63) == 0) cc[k] = s;
}

// Block = 128 z-rows x 2048 codes (16 chunks of 128). Thread tile: 8 rows x 8
// codes, rows STRIDED (row = ty + 16*i) so z b128 reads hit 4 distinct bank
// groups (conflict-free); zt padded to stride 68. All acc chains keep round-6's
// sequential-d fused-FMA order -> bit-identical results.
__global__ __launch_bounds__(256) void VQQuantizer_30064771072206_kernel(
    const float* __restrict__ zf, const float* __restrict__ cb,
    const float* __restrict__ cbt, const float* __restrict__ cc,
    float* __restrict__ loss_acc, float* __restrict__ out)
{
  __shared__ __align__(16) float zt[128 * 68];   // 34816 B, padded row-major
  __shared__ __align__(16) float ct[8192];       // 64 d x 128 codes, 32 KB
  __shared__ float cc_l[128];
  __shared__ float zz_l[128];
  __shared__ int   idxbuf[128];
  __shared__ float wsum[4];
  const int t  = threadIdx.x;
  const int tx = t & 15;                   // code selector
  const int ty = t >> 4;                   // row selector (rows ty+16i)
  const int R0 = blockIdx.x * 128;
  const float4* zf4  = (const float4*)zf;
  const float4* cb4  = (const float4*)cb;
  const float4* cbt4 = (const float4*)cbt;
  float4* ct4 = (float4*)ct;

  // stage z tile (128x64): coalesced float4, padded rows (writes 2-way = free)
  #pragma unroll
  for (int i = 0; i < 8; ++i) {
    int f = i * 256 + t;
    int row = f >> 4, dq = f & 15;
    *(float4*)&zt[row * 68 + dq * 4] = zf4[(size_t)R0 * 16 + f];
  }
  __syncthreads();
  // zz per row: sequential d (bit-identical chain), from global (L1-hot)
  if (t < 128) {
    float s = 0.f;
    for (int d = 0; d < 64; ++d) {
      float v = zf[(size_t)(R0 + t) * 64 + d];
      s += v * v;
    }
    zz_l[t] = s;
  }
  __syncthreads();
  float zz_r[8];
  #pragma unroll
  for (int i = 0; i < 8; ++i) zz_r[i] = zz_l[ty + 16 * i];

  float bestv[8];
  int   besti[8];
  #pragma unroll
  for (int i = 0; i < 8; ++i) { bestv[i] = 3.402823466e38f; besti[i] = 0; }

  #pragma unroll 1
  for (int chunk = 0; chunk < 16; ++chunk) {
    if (chunk) __syncthreads();            // prior chunk fully consumed
    #pragma unroll
    for (int i = 0; i < 8; ++i)            // load->immediate-store staging
      ct4[i * 256 + t] = cbt4[(size_t)chunk * 2048 + i * 256 + t];
    if (t < 128) cc_l[t] = cc[chunk * 128 + t];
    __syncthreads();

    f32x2 A[8][4];
    #pragma unroll
    for (int i = 0; i < 8; ++i)
      #pragma unroll
      for (int j = 0; j < 4; ++j) { A[i][j].x = 0.f; A[i][j].y = 0.f; }

    #pragma unroll
    for (int dg = 0; dg < 16; ++dg) {      // d = dg*4+dd ascending (bit-stable)
      f32x4 zv[8];
      #pragma unroll
      for (int i = 0; i < 8; ++i)          // conflict-free: banks 4*ty distinct
        zv[i] = *(const f32x4*)&zt[(ty + 16 * i) * 68 + dg * 4];
      #pragma unroll
      for (int dd = 0; dd < 4; ++dd) {
        const float* crow = &ct[(dg * 4 + dd) * 128];
        f32x4 ca = *(const f32x4*)&crow[tx * 4];        // 2-way (free)
        f32x4 cbv = *(const f32x4*)&crow[64 + tx * 4];
        f32x2 c0 = ca.xy, c1 = ca.zw, c2 = cbv.xy, c3 = cbv.zw;
        #pragma unroll
        for (int i = 0; i < 8; ++i) {
          float zs = (dd == 0) ? zv[i].x : (dd == 1) ? zv[i].y
                   : (dd == 2) ? zv[i].z : zv[i].w;
          A[i][0] += c0 * zs;              // v_pk_fma_f32: 2 indep chains/instr
          A[i][1] += c1 * zs;
          A[i][2] += c2 * zs;
          A[i][3] += c3 * zs;
        }
      }
    }

    // dist = fl(zz - 2*acc) + cc; per-row ascending code order (np ties)
    #pragma unroll
    for (int jc = 0; jc < 4; ++jc) {
      int cbase = (jc < 2) ? (tx * 4 + jc * 2) : (64 + tx * 4 + (jc - 2) * 2);
      int code0 = chunk * 128 + cbase;
      float cc0 = cc_l[cbase], cc1 = cc_l[cbase + 1];
      #pragma unroll
      for (int i = 0; i < 8; ++i) {
        float t0 = zz_r[i] - 2.0f * A[i][jc].x;
        float d0 = t0 + cc0;
        float t1 = zz_r[i] - 2.0f * A[i][jc].y;
        float d1 = t1 + cc1;
        if (d0 < bestv[i]) { bestv[i] = d0; besti[i] = code0; }
        if (d1 < bestv[i]) { bestv[i] = d1; besti[i] = code0 + 1; }
      }
    }
  }

  // merge across the 16 consecutive lanes sharing a row set (lowest-index ties)
  #pragma unroll
  for (int i = 0; i < 8; ++i) {
    float v = bestv[i]; int idx = besti[i];
    #pragma unroll
    for (int m = 1; m < 16; m <<= 1) {
      float ov = __shfl_xor(v, m, 64);
      int   oi = __shfl_xor(idx, m, 64);
      if (ov < v || (ov == v && oi < idx)) { v = ov; idx = oi; }
    }
    if (tx == 0) idxbuf[ty + 16 * i] = idx;
  }
  __syncthreads();

  if (t < 128) out[IDX_OFF + R0 + t] = (float)idxbuf[t];

  // codes = zg + (zq - zg) (same fp ops as np); loss fp32; all float4
  float lsum = 0.f;
  float4* out4 = (float4*)out;
  #pragma unroll
  for (int i = 0; i < 8; ++i) {
    int f = i * 256 + t;
    int row = f >> 4, dq = f & 15;
    int k = idxbuf[row];                   // uniform per 16 lanes -> broadcast
    float4 q  = cb4[(size_t)k * 16 + dq];
    float4 zv = zf4[(size_t)(R0 + row) * 16 + dq];
    float dx = q.x - zv.x, dy = q.y - zv.y, dz = q.z - zv.z, dw = q.w - zv.w;
    float4 st; st.x = zv.x + dx; st.y = zv.y + dy; st.z = zv.z + dz; st.w = zv.w + dw;
    out4[(size_t)(R0 + row) * 16 + dq] = st;
    lsum += dx * dx; lsum += dy * dy; lsum += dz * dz; lsum += dw * dw;
  }
  #pragma unroll
  for (int m = 1; m < 64; m <<= 1) lsum += __shfl_xor(lsum, m, 64);
  if ((t & 63) == 0) wsum[t >> 6] = lsum;
  __syncthreads();
  if (t == 0) atomicAdd(loss_acc, wsum[0] + wsum[1] + wsum[2] + wsum[3]);
}

__global__ void vq_finalize(const float* __restrict__ loss_acc,
                            float* __restrict__ out) {
  out[LOSS_OFF] = loss_acc[0] * (1.f / 8388608.f);
}

extern "C" void kernel_launch(void* const* d_in, const int* in_sizes, int n_in,
                              void* d_out, int out_size, void* d_ws, size_t ws_size,
                              hipStream_t stream) {
  const float* z  = (const float*)d_in[0];
  const float* cb = (const float*)d_in[1];
  float* out = (float*)d_out;
  float* loss_acc = (float*)d_ws;
  float* cc       = (float*)((char*)d_ws + WS_CC);
  float* cbt      = (float*)((char*)d_ws + WS_CBT);

  vq_prep<<<512, 256, 0, stream>>>(cb, cc, cbt, loss_acc);
  VQQuantizer_30064771072206_kernel<<<1024, 256, 0, stream>>>(z, cb, cbt, cc, loss_acc, out);
  vq_finalize<<<1, 1, 0, stream>>>(loss_acc, out);
}